// Round 2
// baseline (25.171 us; speedup 1.0000x reference)
//
#include <hip/hip_runtime.h>

// LIF forward scan: x [T=32, B=128, N=4096] f32 -> spikes [T, B, N] f32.
// Recurrence per neuron (independent across B*N):
//   v += (x_t - v) / 2;  s = (v - 1 > 0);  v *= (1 - s)
// R1: 2 elems/thread (float2) instead of 4 -> 1024 blocks = 4 waves/SIMD
// (was 2), doubling outstanding-load capacity for this pure-streaming op.
// 8 B/lane is within the coalescing sweet spot.

#define LIF_T 32

__global__ __launch_bounds__(256, 4) void lif_fwd_kernel(const float* __restrict__ x,
                                                         float* __restrict__ out,
                                                         int bn) {
    const int i = (blockIdx.x * blockDim.x + threadIdx.x) * 2;
    if (i >= bn) return;

    float v0 = 0.f, v1 = 0.f;

    #pragma unroll
    for (int t = 0; t < LIF_T; ++t) {
        const size_t off = (size_t)t * (size_t)bn + (size_t)i;
        const float2 xv = *reinterpret_cast<const float2*>(x + off);

        // v = v + (x - v) * 0.5  (matches reference: v + (x_t - v)/tau, tau=2.0)
        v0 = v0 + (xv.x - v0) * 0.5f;
        v1 = v1 + (xv.y - v1) * 0.5f;

        float2 s;
        s.x = (v0 - 1.0f > 0.0f) ? 1.0f : 0.0f;
        s.y = (v1 - 1.0f > 0.0f) ? 1.0f : 0.0f;

        // v *= (1 - s): reset to exactly 0 on spike
        v0 = (s.x != 0.0f) ? 0.0f : v0;
        v1 = (s.y != 0.0f) ? 0.0f : v1;

        *reinterpret_cast<float2*>(out + off) = s;
    }
}

extern "C" void kernel_launch(void* const* d_in, const int* in_sizes, int n_in,
                              void* d_out, int out_size, void* d_ws, size_t ws_size,
                              hipStream_t stream) {
    const float* x = (const float*)d_in[0];
    float* out = (float*)d_out;

    const int total = in_sizes[0];          // T * B * N = 16,777,216
    const int bn = total / LIF_T;           // B * N = 524,288

    const int threads = 256;
    const int elems_per_thread = 2;
    const int nthreads = bn / elems_per_thread;            // 262,144
    const int blocks = (nthreads + threads - 1) / threads; // 1024

    lif_fwd_kernel<<<blocks, threads, 0, stream>>>(x, out, bn);
}

// Round 4
// 23.978 us; speedup vs baseline: 1.0497x; 1.0497x over previous
//
#include <hip/hip_runtime.h>

// LIF forward scan: x [T=32, B=128, N=4096] f32 -> spikes [T, B, N] f32.
// Recurrence per neuron (independent across B*N):
//   v += (x_t - v) / 2;  s = (v - 1 > 0);  v *= (1 - s)
// R3: same as R2 but nontemporal store uses a clang ext_vector_type
// (the builtin rejects HIP_vector_type structs).
//  - float4 geometry (512 blocks, 2 waves/SIMD)
//  - explicit 8-deep load batches (8 global_load_dwordx4 back-to-back)
//  - nontemporal spike stores (written once, never re-read in-kernel)

#define LIF_T 32
#define GRP 8

typedef float floatx4 __attribute__((ext_vector_type(4)));

__global__ __launch_bounds__(256) void lif_fwd_kernel(const float* __restrict__ x,
                                                      float* __restrict__ out,
                                                      int bn) {
    const int i = (blockIdx.x * blockDim.x + threadIdx.x) * 4;
    if (i >= bn) return;

    float v0 = 0.f, v1 = 0.f, v2 = 0.f, v3 = 0.f;

    #pragma unroll
    for (int g = 0; g < LIF_T / GRP; ++g) {
        floatx4 xv[GRP];
        // issue all 8 loads back-to-back (independent addresses)
        #pragma unroll
        for (int k = 0; k < GRP; ++k) {
            const size_t off = (size_t)(g * GRP + k) * (size_t)bn + (size_t)i;
            xv[k] = *reinterpret_cast<const floatx4*>(x + off);
        }
        // consume in order; serial v-chain, stores nontemporal
        #pragma unroll
        for (int k = 0; k < GRP; ++k) {
            v0 = v0 + (xv[k].x - v0) * 0.5f;
            v1 = v1 + (xv[k].y - v1) * 0.5f;
            v2 = v2 + (xv[k].z - v2) * 0.5f;
            v3 = v3 + (xv[k].w - v3) * 0.5f;

            floatx4 s;
            s.x = (v0 - 1.0f > 0.0f) ? 1.0f : 0.0f;
            s.y = (v1 - 1.0f > 0.0f) ? 1.0f : 0.0f;
            s.z = (v2 - 1.0f > 0.0f) ? 1.0f : 0.0f;
            s.w = (v3 - 1.0f > 0.0f) ? 1.0f : 0.0f;

            v0 = (s.x != 0.0f) ? 0.0f : v0;
            v1 = (s.y != 0.0f) ? 0.0f : v1;
            v2 = (s.z != 0.0f) ? 0.0f : v2;
            v3 = (s.w != 0.0f) ? 0.0f : v3;

            const size_t off = (size_t)(g * GRP + k) * (size_t)bn + (size_t)i;
            floatx4* p = reinterpret_cast<floatx4*>(out + off);
            __builtin_nontemporal_store(s, p);
        }
    }
}

extern "C" void kernel_launch(void* const* d_in, const int* in_sizes, int n_in,
                              void* d_out, int out_size, void* d_ws, size_t ws_size,
                              hipStream_t stream) {
    const float* x = (const float*)d_in[0];
    float* out = (float*)d_out;

    const int total = in_sizes[0];          // T * B * N = 16,777,216
    const int bn = total / LIF_T;           // B * N = 524,288

    const int threads = 256;
    const int elems_per_thread = 4;
    const int nthreads = bn / elems_per_thread;            // 131,072
    const int blocks = (nthreads + threads - 1) / threads; // 512

    lif_fwd_kernel<<<blocks, threads, 0, stream>>>(x, out, bn);
}